// Round 3
// baseline (264.791 us; speedup 1.0000x reference)
//
#include <hip/hip_runtime.h>
#include <math.h>

#define FH 256
#define FW 256
#define HW (FH * FW)          // 65536
#define BATCH 16
#define NTGT 256
#define NCH 32
#define EPS_ 1e-7f

__device__ __forceinline__ float sigmoidf_(float x) {
    return 1.0f / (1.0f + expf(-x));
}
__device__ __forceinline__ float softplusf_(float x) {
    return fmaxf(x, 0.0f) + log1pf(expf(-fabsf(x)));
}

// ws layout: [mask: B*HW floats][win: B*HW ints (0=none, else prio+1)][acc: 5 f][counter: 1 int]
// All cleared by ONE memset node.

// ---------------- scatter: assignment priorities + gaussian splat ----------
__global__ __launch_bounds__(256) void scatter_kernel(const float* __restrict__ targets,
                                                      float* __restrict__ mask,
                                                      int* __restrict__ win) {
    int n = blockIdx.x;  // one block per target
    float cx  = targets[n * 6 + 1];
    float cy  = targets[n * 6 + 2];
    float w   = targets[n * 6 + 3];
    float h   = targets[n * 6 + 4];
    int bi = (int)targets[n * 6 + 0];

    if (threadIdx.x == 0) {
        int gi = (int)(cx * (float)FW);
        int gj = (int)(cy * (float)FH);
#pragma unroll
        for (int k = 0; k < 9; ++k) {
            int dxv = k / 3 - 1;   // -1,-1,-1,0,0,0,1,1,1
            int dyv = k % 3 - 1;   // -1,0,1,-1,0,1,-1,0,1
            int nx = gi + dxv, ny = gj + dyv;
            bool inb = (nx >= 0) && (nx < FW) && (ny >= 0) && (ny < FH);
            float ccx = ((float)nx + 0.5f) / (float)FW;
            float ccy = ((float)ny + 0.5f) / (float)FH;
            bool inside = (fabsf(ccx - cx) <= w * 0.5f) && (fabsf(ccy - cy) <= h * 0.5f);
            if (inb && inside) {
                atomicMax(&win[bi * HW + ny * FW + nx], n * 10 + k + 1);
            }
        }
        int cell = min(gj, FH - 1) * FW + min(gi, FW - 1);
        atomicMax(&win[bi * HW + cell], n * 10 + 9 + 1);
    }

    // Gaussian splat: exp(-d2/4.5). Radius 12 truncation error <= e^-32.
    float tx = cx * (float)FW;
    float ty = cy * (float)FH;
    int itx = (int)tx, ity = (int)ty;
    int x0 = max(0, itx - 12), x1 = min(FW - 1, itx + 12);
    int y0 = max(0, ity - 12), y1 = min(FH - 1, ity + 12);
    int nxw = x1 - x0 + 1;
    int tot = nxw * (y1 - y0 + 1);
    unsigned int* mrow = (unsigned int*)(mask + bi * HW);
    for (int i = threadIdx.x; i < tot; i += blockDim.x) {
        int xx = x0 + i % nxw;
        int yy = y0 + i / nxw;
        float ddx = (float)xx - tx;
        float ddy = (float)yy - ty;
        float g = expf(-(ddx * ddx + ddy * ddy) / 4.5f);
        // non-negative floats: uint bit order == float order; init is 0
        atomicMax(&mrow[yy * FW + xx], __float_as_uint(g));
    }
}

// -------- main fused loss kernel: 4 cells/thread + last-block finalize -----
__global__ __launch_bounds__(256) void main_kernel(const float* __restrict__ raw,
                                                   const float* __restrict__ sal,
                                                   const float* __restrict__ targets,
                                                   const float* __restrict__ mask,
                                                   const int* __restrict__ win,
                                                   float* __restrict__ acc,
                                                   int* __restrict__ counter,
                                                   float* __restrict__ out) {
    int q = blockIdx.x * 256 + threadIdx.x;   // q in [0, 262144)
    int base = q << 2;                        // first of 4 consecutive cells
    int b = base >> 16;                       // HW = 65536
    int hw = base & (HW - 1);

    // ---- sal channel-mean over 32 channels (float4 per load) ----
    const float4* sp = (const float4*)(sal + (size_t)b * NCH * HW + hw);
    float4 s = make_float4(0.f, 0.f, 0.f, 0.f);
#pragma unroll
    for (int c = 0; c < NCH; ++c) {
        float4 v = sp[(size_t)c * (HW / 4)];
        s.x += v.x; s.y += v.y; s.z += v.z; s.w += v.w;
    }
    float4 mk = *(const float4*)(mask + base);
    float sm[4]  = {s.x, s.y, s.z, s.w};
    float mkv[4] = {mk.x, mk.y, mk.z, mk.w};

    // ---- raw: 28 floats = 7 float4 loads ----
    float4 rr[7];
    const float4* rp = (const float4*)(raw + (size_t)base * 7);
#pragma unroll
    for (int i = 0; i < 7; ++i) rr[i] = rp[i];
    const float* rf = (const float*)rr;

    int4 wv4 = *(const int4*)(win + base);
    int wvs[4] = {wv4.x - 1, wv4.y - 1, wv4.z - 1, wv4.w - 1};  // decode prio+1

    float attn_s = 0.f, conf_s = 0.f, ciou_s = 0.f, cls_s = 0.f, pos_s = 0.f;
    int x0i = hw & (FW - 1);
    float fy = (float)(hw >> 8);

#pragma unroll
    for (int j = 0; j < 4; ++j) {
        float dmm = sm[j] * (1.0f / 32.0f) - mkv[j];
        attn_s += dmm * dmm;

        const float* r = rf + j * 7;
        float r0 = r[0], r1 = r[1], r2 = r[2], r3 = r[3];
        float z = r[4], l0 = r[5], l1 = r[6];

        float pcx = (sigmoidf_(r0) + (float)(x0i + j)) * (1.0f / (float)FW);
        float pcy = (sigmoidf_(r1) + fy) * (1.0f / (float)FH);
        float pw = expf(fminf(fmaxf(r2, -4.0f), 4.0f)) * (1.0f / (float)FW);
        float ph = expf(fminf(fmaxf(r3, -4.0f), 4.0f)) * (1.0f / (float)FH);
        float conf = sigmoidf_(z);

        int wv = wvs[j];
        if (wv >= 0) {
            pos_s += 1.0f;
            float omc = 1.0f - conf;
            conf_s += 0.25f * omc * omc * softplusf_(-z);

            int t = wv / 10;
            float tcx = targets[t * 6 + 1], tcy = targets[t * 6 + 2];
            float tw = targets[t * 6 + 3], th = targets[t * 6 + 4];
            int cls = (int)targets[t * 6 + 5];

            float px1 = pcx - pw * 0.5f, py1 = pcy - ph * 0.5f;
            float px2 = pcx + pw * 0.5f, py2 = pcy + ph * 0.5f;
            float tx1 = tcx - tw * 0.5f, ty1 = tcy - th * 0.5f;
            float tx2 = tcx + tw * 0.5f, ty2 = tcy + th * 0.5f;
            float iw = fmaxf(fminf(px2, tx2) - fmaxf(px1, tx1), 0.0f);
            float ih = fmaxf(fminf(py2, ty2) - fmaxf(py1, ty1), 0.0f);
            float inter = iw * ih;
            float uni = pw * ph + tw * th - inter;
            float iou = inter / (uni + EPS_);
            float cw = fmaxf(px2, tx2) - fminf(px1, tx1);
            float chh = fmaxf(py2, ty2) - fminf(py1, ty1);
            float c2 = cw * cw + chh * chh + EPS_;
            float dcx = pcx - tcx, dcy = pcy - tcy;
            float d2 = dcx * dcx + dcy * dcy;
            float dv = atanf(tw / (th + EPS_)) - atanf(pw / (ph + EPS_));
            float v = (4.0f / (float)(M_PI * M_PI)) * dv * dv;
            float alpha = v / (1.0f - iou + v + EPS_);
            ciou_s += 1.0f - iou + d2 / c2 + alpha * v;

            float m_ = fmaxf(l0, l1);
            float lse = m_ + logf(expf(l0 - m_) + expf(l1 - m_));
            cls_s += lse - ((cls == 0) ? l0 : l1);
        } else {
            conf_s += 0.75f * conf * conf * softplusf_(z);
        }
    }

    // ---- block reduction of 5 sums, one atomicAdd set per block ----
    float vals[5] = {attn_s, conf_s, ciou_s, cls_s, pos_s};
#pragma unroll
    for (int jj = 0; jj < 5; ++jj) {
        float v = vals[jj];
#pragma unroll
        for (int o = 32; o > 0; o >>= 1) v += __shfl_down(v, o, 64);
        vals[jj] = v;
    }
    __shared__ float red[4][5];
    int lane = threadIdx.x & 63;
    int wid = threadIdx.x >> 6;
    if (lane == 0) {
#pragma unroll
        for (int jj = 0; jj < 5; ++jj) red[wid][jj] = vals[jj];
    }
    __syncthreads();
    if (threadIdx.x < 5) {
        float v = red[0][threadIdx.x] + red[1][threadIdx.x] +
                  red[2][threadIdx.x] + red[3][threadIdx.x];
        atomicAdd(&acc[threadIdx.x], v);
    }
    __syncthreads();

    // ---- last block finalizes (fused epilogue) ----
    if (threadIdx.x == 0) {
        __threadfence();
        int old = atomicAdd(counter, 1);
        if (old == (int)gridDim.x - 1) {
            __threadfence();
            // atomic reads: device-scope coherent view of acc
            float attn = atomicAdd(&acc[0], 0.0f);
            float conf = atomicAdd(&acc[1], 0.0f);
            float ciou = atomicAdd(&acc[2], 0.0f);
            float cls  = atomicAdd(&acc[3], 0.0f);
            float npos = atomicAdd(&acc[4], 0.0f);
            float norm = fmaxf(npos, 1.0f);
            out[0] = (2.0f * ciou + conf + cls) / norm +
                     5.0f * (attn * (1.0f / (float)(BATCH * HW)));
        }
    }
}

extern "C" void kernel_launch(void* const* d_in, const int* in_sizes, int n_in,
                              void* d_out, int out_size, void* d_ws, size_t ws_size,
                              hipStream_t stream) {
    const float* raw = (const float*)d_in[0];      // (16, 65536, 7)
    const float* sal = (const float*)d_in[1];      // (16, 32, 256, 256)
    const float* targets = (const float*)d_in[2];  // (256, 6)
    float* out = (float*)d_out;

    char* ws = (char*)d_ws;
    float* mask = (float*)ws;                                     // 4 MB
    int* win = (int*)(ws + (size_t)BATCH * HW * 4);               // 4 MB
    float* acc = (float*)(ws + (size_t)BATCH * HW * 8);           // 5 floats
    int* counter = (int*)(ws + (size_t)BATCH * HW * 8 + 5 * 4);   // 1 int

    // One clear covers mask(0.0f) + win(0 = no winner) + acc(0) + counter(0)
    hipMemsetAsync(ws, 0, (size_t)BATCH * HW * 8 + 64, stream);

    scatter_kernel<<<NTGT, 256, 0, stream>>>(targets, mask, win);

    const int NBLK = (BATCH * HW / 4) / 256;  // 1024
    main_kernel<<<NBLK, 256, 0, stream>>>(raw, sal, targets, mask, win, acc, counter, out);
}

// Round 4
// 226.868 us; speedup vs baseline: 1.1672x; 1.1672x over previous
//
#include <hip/hip_runtime.h>
#include <math.h>

#define FH 256
#define FW 256
#define HW (FH * FW)          // 65536
#define BATCH 16
#define NTGT 256
#define NCH 32
#define EPS_ 1e-7f

__device__ __forceinline__ float sigmoidf_(float x) {
    return 1.0f / (1.0f + expf(-x));
}
__device__ __forceinline__ float softplusf_(float x) {
    return fmaxf(x, 0.0f) + log1pf(expf(-fabsf(x)));
}

// ws layout:
//   [mask: B*HW floats][win: B*HW ints (0=none, else prio+1)][partials: NBLK*5 floats]
// mask+win cleared by ONE memset node (0.0f / 0 both all-zero bytes).
// partials are fully overwritten by main_kernel (no init needed).

// ---------------- scatter: assignment priorities + gaussian splat ----------
__global__ __launch_bounds__(256) void scatter_kernel(const float* __restrict__ targets,
                                                      float* __restrict__ mask,
                                                      int* __restrict__ win) {
    int n = blockIdx.x;  // one block per target
    float cx  = targets[n * 6 + 1];
    float cy  = targets[n * 6 + 2];
    float w   = targets[n * 6 + 3];
    float h   = targets[n * 6 + 4];
    int bi = (int)targets[n * 6 + 0];

    if (threadIdx.x == 0) {
        int gi = (int)(cx * (float)FW);
        int gj = (int)(cy * (float)FH);
#pragma unroll
        for (int k = 0; k < 9; ++k) {
            int dxv = k / 3 - 1;   // -1,-1,-1,0,0,0,1,1,1
            int dyv = k % 3 - 1;   // -1,0,1,-1,0,1,-1,0,1
            int nx = gi + dxv, ny = gj + dyv;
            bool inb = (nx >= 0) && (nx < FW) && (ny >= 0) && (ny < FH);
            float ccx = ((float)nx + 0.5f) / (float)FW;
            float ccy = ((float)ny + 0.5f) / (float)FH;
            bool inside = (fabsf(ccx - cx) <= w * 0.5f) && (fabsf(ccy - cy) <= h * 0.5f);
            if (inb && inside) {
                atomicMax(&win[bi * HW + ny * FW + nx], n * 10 + k + 1);
            }
        }
        int cell = min(gj, FH - 1) * FW + min(gi, FW - 1);
        atomicMax(&win[bi * HW + cell], n * 10 + 9 + 1);
    }

    // Gaussian splat: exp(-d2/4.5). Radius 12 truncation error <= e^-32.
    float tx = cx * (float)FW;
    float ty = cy * (float)FH;
    int itx = (int)tx, ity = (int)ty;
    int x0 = max(0, itx - 12), x1 = min(FW - 1, itx + 12);
    int y0 = max(0, ity - 12), y1 = min(FH - 1, ity + 12);
    int nxw = x1 - x0 + 1;
    int tot = nxw * (y1 - y0 + 1);
    unsigned int* mrow = (unsigned int*)(mask + bi * HW);
    for (int i = threadIdx.x; i < tot; i += blockDim.x) {
        int xx = x0 + i % nxw;
        int yy = y0 + i / nxw;
        float ddx = (float)xx - tx;
        float ddy = (float)yy - ty;
        float g = expf(-(ddx * ddx + ddy * ddy) / 4.5f);
        // non-negative floats: uint bit order == float order; init is 0
        atomicMax(&mrow[yy * FW + xx], __float_as_uint(g));
    }
}

// -------- main fused loss kernel: 4 cells/thread, contention-free output ---
__global__ __launch_bounds__(256) void main_kernel(const float* __restrict__ raw,
                                                   const float* __restrict__ sal,
                                                   const float* __restrict__ targets,
                                                   const float* __restrict__ mask,
                                                   const int* __restrict__ win,
                                                   float* __restrict__ partials) {
    int q = blockIdx.x * 256 + threadIdx.x;   // q in [0, 262144)
    int base = q << 2;                        // first of 4 consecutive cells
    int b = base >> 16;                       // HW = 65536
    int hw = base & (HW - 1);

    // ---- sal channel-mean over 32 channels (float4 per load) ----
    const float4* sp = (const float4*)(sal + (size_t)b * NCH * HW + hw);
    float4 s = make_float4(0.f, 0.f, 0.f, 0.f);
#pragma unroll
    for (int c = 0; c < NCH; ++c) {
        float4 v = sp[(size_t)c * (HW / 4)];
        s.x += v.x; s.y += v.y; s.z += v.z; s.w += v.w;
    }
    float4 mk = *(const float4*)(mask + base);
    float sm[4]  = {s.x, s.y, s.z, s.w};
    float mkv[4] = {mk.x, mk.y, mk.z, mk.w};

    // ---- raw: 28 floats = 7 float4 loads ----
    float4 rr[7];
    const float4* rp = (const float4*)(raw + (size_t)base * 7);
#pragma unroll
    for (int i = 0; i < 7; ++i) rr[i] = rp[i];
    const float* rf = (const float*)rr;

    int4 wv4 = *(const int4*)(win + base);
    int wvs[4] = {wv4.x - 1, wv4.y - 1, wv4.z - 1, wv4.w - 1};  // decode prio+1

    float attn_s = 0.f, conf_s = 0.f, ciou_s = 0.f, cls_s = 0.f, pos_s = 0.f;
    int x0i = hw & (FW - 1);
    float fy = (float)(hw >> 8);

#pragma unroll
    for (int j = 0; j < 4; ++j) {
        float dmm = sm[j] * (1.0f / 32.0f) - mkv[j];
        attn_s += dmm * dmm;

        const float* r = rf + j * 7;
        float r0 = r[0], r1 = r[1], r2 = r[2], r3 = r[3];
        float z = r[4], l0 = r[5], l1 = r[6];

        float pcx = (sigmoidf_(r0) + (float)(x0i + j)) * (1.0f / (float)FW);
        float pcy = (sigmoidf_(r1) + fy) * (1.0f / (float)FH);
        float pw = expf(fminf(fmaxf(r2, -4.0f), 4.0f)) * (1.0f / (float)FW);
        float ph = expf(fminf(fmaxf(r3, -4.0f), 4.0f)) * (1.0f / (float)FH);
        float conf = sigmoidf_(z);

        int wv = wvs[j];
        if (wv >= 0) {
            pos_s += 1.0f;
            float omc = 1.0f - conf;
            conf_s += 0.25f * omc * omc * softplusf_(-z);

            int t = wv / 10;
            float tcx = targets[t * 6 + 1], tcy = targets[t * 6 + 2];
            float tw = targets[t * 6 + 3], th = targets[t * 6 + 4];
            int cls = (int)targets[t * 6 + 5];

            float px1 = pcx - pw * 0.5f, py1 = pcy - ph * 0.5f;
            float px2 = pcx + pw * 0.5f, py2 = pcy + ph * 0.5f;
            float tx1 = tcx - tw * 0.5f, ty1 = tcy - th * 0.5f;
            float tx2 = tcx + tw * 0.5f, ty2 = tcy + th * 0.5f;
            float iw = fmaxf(fminf(px2, tx2) - fmaxf(px1, tx1), 0.0f);
            float ih = fmaxf(fminf(py2, ty2) - fmaxf(py1, ty1), 0.0f);
            float inter = iw * ih;
            float uni = pw * ph + tw * th - inter;
            float iou = inter / (uni + EPS_);
            float cw = fmaxf(px2, tx2) - fminf(px1, tx1);
            float chh = fmaxf(py2, ty2) - fminf(py1, ty1);
            float c2 = cw * cw + chh * chh + EPS_;
            float dcx = pcx - tcx, dcy = pcy - tcy;
            float d2 = dcx * dcx + dcy * dcy;
            float dv = atanf(tw / (th + EPS_)) - atanf(pw / (ph + EPS_));
            float v = (4.0f / (float)(M_PI * M_PI)) * dv * dv;
            float alpha = v / (1.0f - iou + v + EPS_);
            ciou_s += 1.0f - iou + d2 / c2 + alpha * v;

            float m_ = fmaxf(l0, l1);
            float lse = m_ + logf(expf(l0 - m_) + expf(l1 - m_));
            cls_s += lse - ((cls == 0) ? l0 : l1);
        } else {
            conf_s += 0.75f * conf * conf * softplusf_(z);
        }
    }

    // ---- block reduction of 5 sums; plain store to distinct addresses ----
    float vals[5] = {attn_s, conf_s, ciou_s, cls_s, pos_s};
#pragma unroll
    for (int jj = 0; jj < 5; ++jj) {
        float v = vals[jj];
#pragma unroll
        for (int o = 32; o > 0; o >>= 1) v += __shfl_down(v, o, 64);
        vals[jj] = v;
    }
    __shared__ float red[4][5];
    int lane = threadIdx.x & 63;
    int wid = threadIdx.x >> 6;
    if (lane == 0) {
#pragma unroll
        for (int jj = 0; jj < 5; ++jj) red[wid][jj] = vals[jj];
    }
    __syncthreads();
    if (threadIdx.x < 5) {
        partials[blockIdx.x * 5 + threadIdx.x] =
            red[0][threadIdx.x] + red[1][threadIdx.x] +
            red[2][threadIdx.x] + red[3][threadIdx.x];
    }
}

// ---------------- finalize: reduce 1024x5 partials, combine loss ----------
__global__ __launch_bounds__(256) void finalize_kernel(const float* __restrict__ partials,
                                                       int nblk, float* __restrict__ out) {
    float acc[5] = {0.f, 0.f, 0.f, 0.f, 0.f};
    for (int i = threadIdx.x; i < nblk; i += 256) {
#pragma unroll
        for (int j = 0; j < 5; ++j) acc[j] += partials[i * 5 + j];
    }
#pragma unroll
    for (int j = 0; j < 5; ++j) {
        float v = acc[j];
#pragma unroll
        for (int o = 32; o > 0; o >>= 1) v += __shfl_down(v, o, 64);
        acc[j] = v;
    }
    __shared__ float red[4][5];
    int lane = threadIdx.x & 63;
    int wid = threadIdx.x >> 6;
    if (lane == 0) {
#pragma unroll
        for (int j = 0; j < 5; ++j) red[wid][j] = acc[j];
    }
    __syncthreads();
    if (threadIdx.x == 0) {
        float attn = red[0][0] + red[1][0] + red[2][0] + red[3][0];
        float conf = red[0][1] + red[1][1] + red[2][1] + red[3][1];
        float ciou = red[0][2] + red[1][2] + red[2][2] + red[3][2];
        float cls  = red[0][3] + red[1][3] + red[2][3] + red[3][3];
        float npos = red[0][4] + red[1][4] + red[2][4] + red[3][4];
        float norm = fmaxf(npos, 1.0f);
        out[0] = (2.0f * ciou + conf + cls) / norm +
                 5.0f * (attn * (1.0f / (float)(BATCH * HW)));
    }
}

extern "C" void kernel_launch(void* const* d_in, const int* in_sizes, int n_in,
                              void* d_out, int out_size, void* d_ws, size_t ws_size,
                              hipStream_t stream) {
    const float* raw = (const float*)d_in[0];      // (16, 65536, 7)
    const float* sal = (const float*)d_in[1];      // (16, 32, 256, 256)
    const float* targets = (const float*)d_in[2];  // (256, 6)
    float* out = (float*)d_out;

    char* ws = (char*)d_ws;
    float* mask = (float*)ws;                               // 4 MB
    int* win = (int*)(ws + (size_t)BATCH * HW * 4);         // 4 MB
    float* partials = (float*)(ws + (size_t)BATCH * HW * 8);// 1024*5 floats

    // One clear covers mask(0.0f) + win(0 = no winner)
    hipMemsetAsync(ws, 0, (size_t)BATCH * HW * 8, stream);

    scatter_kernel<<<NTGT, 256, 0, stream>>>(targets, mask, win);

    const int NBLK = (BATCH * HW / 4) / 256;  // 1024
    main_kernel<<<NBLK, 256, 0, stream>>>(raw, sal, targets, mask, win, partials);
    finalize_kernel<<<1, 256, 0, stream>>>(partials, NBLK, out);
}